// Round 18
// baseline (79.805 us; speedup 1.0000x reference)
//
#include <hip/hip_runtime.h>
#include <hip/hip_bf16.h>

typedef __attribute__((ext_vector_type(8))) short bf16x8;
typedef __attribute__((ext_vector_type(4))) float f32x4;
typedef __attribute__((ext_vector_type(16))) float f32x16;

static __device__ __forceinline__ unsigned short f2bf(float f) {
  union { float f; unsigned int u; } v; v.f = f;
  unsigned int u = v.u;
  return (unsigned short)((u + 0x7FFFu + ((u >> 16) & 1u)) >> 16);
}

__device__ __forceinline__ void async_ld16(const void* g, void* l) {
  __builtin_amdgcn_global_load_lds(
      (const __attribute__((address_space(1))) unsigned int*)g,
      (__attribute__((address_space(3))) unsigned int*)l, 16, 0, 0);
}

// fp32 -> bf16. x -> linear x_bf; Wk/Wq/Wv -> B4-tiled wkqv4 (rows 0..2303,
// Wq scaled by 0.125*log2e); Wo -> B4-tiled wo4. B4: [m/16][k/32][16][32].
__global__ __launch_bounds__(256) void cvt_all(
    const float* __restrict__ x, const float* __restrict__ wk,
    const float* __restrict__ wq, const float* __restrict__ wv,
    const float* __restrict__ wo,
    unsigned short* __restrict__ x_bf, unsigned short* __restrict__ wkqv4,
    unsigned short* __restrict__ wo4) {
  int i = blockIdx.x * 256 + threadIdx.x;
  int e0 = i * 4;
  if (e0 < 3145728) {
    float4 v = *(const float4*)(x + e0);
    ushort4 r;
    r.x = f2bf(v.x); r.y = f2bf(v.y); r.z = f2bf(v.z); r.w = f2bf(v.w);
    *(ushort4*)(x_bf + e0) = r;
    return;
  }
  int j = e0 - 3145728;
  int a = j / 589824;
  int off = j - a * 589824;
  int nl = off / 768;
  int k = off - nl * 768;
  const float* src;
  unsigned short* dst;
  int m;
  float scale = 1.0f;
  if (a == 0)      { src = wk; m = nl;        dst = wkqv4; }
  else if (a == 1) { src = wq; m = 768 + nl;  dst = wkqv4; scale = 0.18033688011112042f; }
  else if (a == 2) { src = wv; m = 1536 + nl; dst = wkqv4; }
  else             { src = wo; m = nl;        dst = wo4; }
  float4 v = *(const float4*)(src + off);
  long idx = ((long)(m >> 4) * 24 + (k >> 5)) * 512 + (m & 15) * 32 + (k & 31);
  ushort4 r;
  r.x = f2bf(v.x * scale); r.y = f2bf(v.y * scale);
  r.z = f2bf(v.z * scale); r.w = f2bf(v.w * scale);
  *(ushort4*)(dst + idx) = r;
}

// 128x96 tile GEMM, BK=64. A: row-major, dbuf LDS (2x16KB), counted vmcnt.
// B: B4 fragment-tiled, register-direct with 1-deep prefetch (named sets).
// ONE barrier per K-step (WAR on As[cur^1] ordered by the next step's barrier).
// vmcnt(6) at step k retires {B_k(6), stage_k(4)} leaving B_{k+1}(6) in flight.
// MODE 0: fused QKV epilogue; MODE 1: fp32 linear out.
template <int MODE>
__device__ __forceinline__ void gemm_body(
    const unsigned short* __restrict__ A,
    const unsigned short* __restrict__ B4,
    void* __restrict__ outK, void* __restrict__ outQ, void* __restrict__ outV,
    int m0, int n0,
    unsigned short (*As)[8192]) {
  const int tid = threadIdx.x;
  const int w = tid >> 6;
  const int l = tid & 63;
  const int g = l >> 4;
  const int c = l & 15;
  const int wr = w >> 1, wc = w & 1;

  f32x4 acc[4][3];
#pragma unroll
  for (int i = 0; i < 4; i++)
#pragma unroll
    for (int j = 0; j < 3; j++) acc[i][j] = (f32x4){0.f, 0.f, 0.f, 0.f};

  const int lrow = l >> 3;
  const int lcolx = ((l & 7) ^ lrow) * 8;
  const unsigned short* pB = B4 + (long)((n0 >> 4) + wc * 3) * 12288 + c * 32 + g * 8;

  auto stageA = [&](int buf, int kt) {
    const int k0 = kt * 64;
#pragma unroll
    for (int cc = 0; cc < 4; ++cc) {
      int chunk = cc * 4 + w;                 // 16 chunks of 8 rows x 64 cols
      int row = chunk * 8 + lrow;
      async_ld16(A + (long)(m0 + row) * 768 + k0 + lcolx, &As[buf][chunk * 512]);
    }
  };
  auto loadB = [&](bf16x8 (*b)[3], int kt) {
#pragma unroll
    for (int ks = 0; ks < 2; ++ks)
#pragma unroll
      for (int ni = 0; ni < 3; ++ni)
        b[ks][ni] = *(const bf16x8*)(pB + (long)ni * 12288 + (kt * 2 + ks) * 512);
  };

  bf16x8 b0[2][3], b1[2][3];
  stageA(0, 0);
  loadB(b0, 0);

#pragma unroll
  for (int kt = 0; kt < 12; kt += 2) {
    // ---- even step kt (buf 0, uses b0) ----
    if (kt + 1 < 12) loadB(b1, kt + 1);
    __builtin_amdgcn_sched_barrier(0);
    asm volatile("s_waitcnt vmcnt(6)" ::: "memory");
    __builtin_amdgcn_sched_barrier(0);
    __builtin_amdgcn_s_barrier();
    __builtin_amdgcn_sched_barrier(0);
    if (kt + 1 < 12) stageA(1, kt + 1);
#pragma unroll
    for (int ks = 0; ks < 2; ++ks) {
      bf16x8 a[4];
#pragma unroll
      for (int mi = 0; mi < 4; ++mi) {
        int row = wr * 64 + mi * 16 + c;
        int col = (ks * 32 + g * 8) ^ ((row & 7) * 8);
        a[mi] = *(const bf16x8*)&As[0][row * 64 + col];
      }
#pragma unroll
      for (int mi = 0; mi < 4; ++mi)
#pragma unroll
        for (int ni = 0; ni < 3; ++ni)
          acc[mi][ni] = __builtin_amdgcn_mfma_f32_16x16x32_bf16(a[mi], b0[ks][ni], acc[mi][ni], 0, 0, 0);
    }
    // ---- odd step kt+1 (buf 1, uses b1) ----
    if (kt + 2 < 12) loadB(b0, kt + 2);
    __builtin_amdgcn_sched_barrier(0);
    if (kt + 2 < 12) {
      asm volatile("s_waitcnt vmcnt(6)" ::: "memory");
    } else {
      asm volatile("s_waitcnt vmcnt(0)" ::: "memory");
    }
    __builtin_amdgcn_sched_barrier(0);
    __builtin_amdgcn_s_barrier();
    __builtin_amdgcn_sched_barrier(0);
    if (kt + 2 < 12) stageA(0, kt + 2);
#pragma unroll
    for (int ks = 0; ks < 2; ++ks) {
      bf16x8 a[4];
#pragma unroll
      for (int mi = 0; mi < 4; ++mi) {
        int row = wr * 64 + mi * 16 + c;
        int col = (ks * 32 + g * 8) ^ ((row & 7) * 8);
        a[mi] = *(const bf16x8*)&As[1][row * 64 + col];
      }
#pragma unroll
      for (int mi = 0; mi < 4; ++mi)
#pragma unroll
        for (int ni = 0; ni < 3; ++ni)
          acc[mi][ni] = __builtin_amdgcn_mfma_f32_16x16x32_bf16(a[mi], b1[ks][ni], acc[mi][ni], 0, 0, 0);
    }
  }

  if (MODE == 1) {
    float* O = (float*)outK;
#pragma unroll
    for (int mi = 0; mi < 4; ++mi)
#pragma unroll
      for (int ni = 0; ni < 3; ++ni)
#pragma unroll
        for (int r = 0; r < 4; ++r) {
          int m = m0 + wr * 64 + mi * 16 + g * 4 + r;
          int n = n0 + wc * 48 + ni * 16 + c;
          O[(long)m * 768 + n] = acc[mi][ni][r];
        }
  } else {
    const int which = (n0 >= 1536) ? 2 : (n0 >= 768 ? 1 : 0);
    const int nb = n0 - which * 768;
    const int b = m0 >> 11;                    // block-uniform
    if (which == 2) {
      // V4 tiled [bh][p/16][e][p&15]: r=0..3 contiguous in p&15 -> ushort4
#pragma unroll
      for (int mi = 0; mi < 4; ++mi)
#pragma unroll
        for (int ni = 0; ni < 3; ++ni) {
          int e = nb + wc * 48 + ni * 16 + c;
          int h = e >> 6, el = e & 63;
          long bh = b * 12 + h;
          int p0 = (m0 & 2047) + wr * 64 + mi * 16 + g * 4;
          long idx = bh * 131072 + (p0 >> 4) * 1024 + el * 16 + (p0 & 15);
          ushort4 pk;
          pk.x = f2bf(acc[mi][ni][0]); pk.y = f2bf(acc[mi][ni][1]);
          pk.z = f2bf(acc[mi][ni][2]); pk.w = f2bf(acc[mi][ni][3]);
          *(ushort4*)&((unsigned short*)outV)[idx] = pk;
        }
    } else {
#pragma unroll
      for (int mi = 0; mi < 4; ++mi)
#pragma unroll
        for (int ni = 0; ni < 3; ++ni)
#pragma unroll
          for (int r = 0; r < 4; ++r) {
            int m = m0 + wr * 64 + mi * 16 + g * 4 + r;
            int nn = nb + wc * 48 + ni * 16 + c;
            int p = m & 2047;
            int h = nn >> 6, e = nn & 63;
            unsigned short val = f2bf(acc[mi][ni][r]);
            long bh = b * 12 + h;
            if (which == 0) {
              // K4 tiled: [bh][p/32][d/16][p&31][d&15]
              long idx = bh * 131072 + (p >> 5) * 2048 + (e >> 4) * 512 + (p & 31) * 16 + (e & 15);
              ((unsigned short*)outK)[idx] = val;
            } else {
              ((unsigned short*)outQ)[((bh * 2048 + p) << 6) + e] = val;
            }
          }
    }
  }
}

// grid 768 (1D) = 3 blocks/CU. XCD-chunked: xcd = bid&7 owns 8m x 12n panel.
__global__ __launch_bounds__(256) void gemm_qkv(
    const unsigned short* __restrict__ A,
    const unsigned short* __restrict__ Wkqv4,  // B4-tiled [Wk;Wq;Wv]
    unsigned short* __restrict__ k4b, unsigned short* __restrict__ qb,
    unsigned short* __restrict__ v4b) {
  __shared__ __align__(16) unsigned short As[2][8192];
  const int lb = blockIdx.x;
  const int xcd = lb & 7, idx = lb >> 3;       // idx 0..95
  const int mg = xcd >> 1, ng = xcd & 1;
  const int mi = idx / 12, ni = idx - 12 * mi; // ni fastest shares A-tile
  gemm_body<0>(A, Wkqv4, k4b, qb, v4b, (mg * 8 + mi) * 128, (ng * 12 + ni) * 96, As);
}

// grid 256 (1D) = 1 block/CU. xcd = bid&7 owns 4m x 8n panel.
__global__ __launch_bounds__(256) void gemm_out(
    const unsigned short* __restrict__ A,
    const unsigned short* __restrict__ Wo4,
    float* __restrict__ out) {
  __shared__ __align__(16) unsigned short As[2][8192];
  const int lb = blockIdx.x;
  const int xcd = lb & 7, idx = lb >> 3;       // idx 0..31
  const int mi = idx >> 3, ni = idx & 7;
  gemm_body<1>(A, Wo4, out, nullptr, nullptr, (xcd * 4 + mi) * 128, ni * 96, As);
}

// causal flash attention: swapped QK^T (32x32x16), in-register softmax,
// DUAL-CHUNK FUSED. Round 18: single K/V register set (no 2-deep rotation,
// -32 VGPR) + __launch_bounds__(256,3) -> 12 waves/CU, grid 768 = 3 blocks/CU
// single pass. Latency hiding via TLP (m114) instead of per-wave prefetch.
__global__ __launch_bounds__(256, 3) void attn(
    const unsigned short* __restrict__ Q,
    const unsigned short* __restrict__ K4,
    const unsigned short* __restrict__ V4,
    unsigned short* __restrict__ Z) {
  __shared__ float2 Opart[3][2][16][64];
  __shared__ float Lpart[3][2][32];
  __shared__ float Linv[2][32];
  const int bx = blockIdx.x;                   // 0..767
  const int cidx = bx / 24;                    // 0..31 (pair index)
  const int bh = bx - cidx * 24;               // bh fastest (round-13 proven)
  const int pp = 31 - cidx;                    // LPT: big pairs first
  const int c0 = 2 * pp, c1 = 2 * pp + 1;
  const int tid = threadIdx.x;
  const int w = tid >> 6;                      // k-parity 0..3
  const int l = tid & 63;
  const int ql = l & 31;
  const int hi = l >> 5;
  const int b = bh / 12, hd = bh - b * 12;
  const long base = (long)bh * 2048 * 64;

  // Q B-fragments for both chunks
  bf16x8 qf0[4], qf1[4];
  {
    const unsigned short* qp0 = Q + base + (long)(c0 * 32 + ql) * 64 + hi * 8;
    const unsigned short* qp1 = Q + base + (long)(c1 * 32 + ql) * 64 + hi * 8;
#pragma unroll
    for (int d = 0; d < 4; ++d) {
      qf0[d] = *(const bf16x8*)(qp0 + d * 16);
      qf1[d] = *(const bf16x8*)(qp1 + d * 16);
    }
  }

  f32x16 oA0, oA1, oB0, oB1;
#pragma unroll
  for (int r = 0; r < 16; ++r) { oA0[r] = 0.f; oA1[r] = 0.f; oB0[r] = 0.f; oB1[r] = 0.f; }
  float ls0 = 0.f, ls1 = 0.f;

  const unsigned short* kp = K4 + (long)bh * 131072 + ql * 16 + hi * 8;
  const unsigned short* vp = V4 + (long)bh * 131072 + ql * 16 + hi * 8;

  for (int s = w; s <= c1; s += 4) {
    // ---- load K/V fragments for subtile s (single set) ----
    bf16x8 kf[4], v0[2], v1[2];
    {
      const unsigned short* kps = kp + (long)s * 2048;
#pragma unroll
      for (int d = 0; d < 4; ++d) kf[d] = *(const bf16x8*)(kps + d * 512);
      const unsigned short* vps = vp + (long)s * 2048;
      v0[0] = *(const bf16x8*)(vps);
      v0[1] = *(const bf16x8*)(vps + 1024);
      v1[0] = *(const bf16x8*)(vps + 512);
      v1[1] = *(const bf16x8*)(vps + 1536);
    }
    const bool do0 = (s <= c0);
    // ---- QK for BOTH chunks first: two independent MFMA chains ----
    f32x16 s1_, s0_;
#pragma unroll
    for (int r = 0; r < 16; ++r) { s1_[r] = 0.f; s0_[r] = 0.f; }
#pragma unroll
    for (int d = 0; d < 4; ++d)
      s1_ = __builtin_amdgcn_mfma_f32_32x32x16_bf16(kf[d], qf1[d], s1_, 0, 0, 0);
    if (do0) {
#pragma unroll
      for (int d = 0; d < 4; ++d)
        s0_ = __builtin_amdgcn_mfma_f32_32x32x16_bf16(kf[d], qf0[d], s0_, 0, 0, 0);
    }
    // ---- chunk1: mask, softmax, PV ----
    if (s == c1) {
#pragma unroll
      for (int r = 0; r < 16; ++r) {
        int krow = (r & 3) + 8 * (r >> 2) + 4 * hi;
        s1_[r] = (krow <= ql) ? s1_[r] : -1e30f;
      }
    }
    {
      float p[16];
#pragma unroll
      for (int r = 0; r < 16; ++r) { p[r] = exp2f(s1_[r]); ls1 += p[r]; }
      unsigned int wpk[8];
#pragma unroll
      for (int i = 0; i < 8; ++i)
        asm("v_cvt_pk_bf16_f32 %0, %1, %2" : "=v"(wpk[i]) : "v"(p[2 * i]), "v"(p[2 * i + 1]));
      asm volatile("v_permlane32_swap_b32 %0, %1" : "+v"(wpk[0]), "+v"(wpk[2]));
      asm volatile("v_permlane32_swap_b32 %0, %1" : "+v"(wpk[1]), "+v"(wpk[3]));
      asm volatile("v_permlane32_swap_b32 %0, %1" : "+v"(wpk[4]), "+v"(wpk[6]));
      asm volatile("v_permlane32_swap_b32 %0, %1" : "+v"(wpk[5]), "+v"(wpk[7]));
      union { unsigned int u[4]; bf16x8 v; } f0, f1;
      f0.u[0] = wpk[0]; f0.u[1] = wpk[1]; f0.u[2] = wpk[2]; f0.u[3] = wpk[3];
      f1.u[0] = wpk[4]; f1.u[1] = wpk[5]; f1.u[2] = wpk[6]; f1.u[3] = wpk[7];
      oB0 = __builtin_amdgcn_mfma_f32_32x32x16_bf16(f0.v, v0[0], oB0, 0, 0, 0);
      oB1 = __builtin_amdgcn_mfma_f32_32x32x16_bf16(f0.v, v1[0], oB1, 0, 0, 0);
      oB0 = __builtin_amdgcn_mfma_f32_32x32x16_bf16(f1.v, v0[1], oB0, 0, 0, 0);
      oB1 = __builtin_amdgcn_mfma_f32_32x32x16_bf16(f1.v, v1[1], oB1, 0, 0, 0);
    }
    // ---- chunk0: mask, softmax, PV ----
    if (do0) {
      if (s == c0) {
#pragma unroll
        for (int r = 0; r < 16; ++r) {
          int krow = (r & 3) + 8 * (r >> 2) + 4 * hi;
          s0_[r] = (krow <= ql) ? s0_[r] : -1e30f;
        }
      }
      float p[16];
#pragma unroll
      for (int r = 0; r < 16; ++r) { p[r] = exp2f(s0_[r]); ls0 += p[r]; }
      unsigned int wpk[8];
#pragma unroll
      for (int i = 0; i < 8; ++i)
        asm("v_cvt_pk_bf16_f32 %0, %1, %2" : "=v"(wpk[i]) : "v"(p[2 * i]), "v"(p[2 * i + 1]));
      asm volatile("v_permlane32_swap_b32 %0, %1" : "+v"(wpk[0]), "+v"(wpk[2]));
      asm volatile("v_permlane32_swap_b32 %0, %1" : "+v"(wpk[1]), "+v"(wpk[3]));
      asm volatile("v_permlane32_swap_b32 %0, %1" : "+v"(wpk[4]), "+v"(wpk[6]));
      asm volatile("v_permlane32_swap_b32 %0, %1" : "+v"(wpk[5]), "+v"(wpk[7]));
      union { unsigned int u[4]; bf16x8 v; } f0, f1;
      f0.u[0] = wpk[0]; f0.u[1] = wpk[1]; f0.u[2] = wpk[2]; f0.u[3] = wpk[3];
      f1.u[0] = wpk[4]; f1.u[1] = wpk[5]; f1.u[2] = wpk[6]; f1.u[3] = wpk[7];
      oA0 = __builtin_amdgcn_mfma_f32_32x32x16_bf16(f0.v, v0[0], oA0, 0, 0, 0);
      oA1 = __builtin_amdgcn_mfma_f32_32x32x16_bf16(f0.v, v1[0], oA1, 0, 0, 0);
      oA0 = __builtin_amdgcn_mfma_f32_32x32x16_bf16(f1.v, v0[1], oA0, 0, 0, 0);
      oA1 = __builtin_amdgcn_mfma_f32_32x32x16_bf16(f1.v, v1[1], oA1, 0, 0, 0);
    }
  }

  ls0 += __shfl_xor(ls0, 32);
  ls1 += __shfl_xor(ls1, 32);

  if (w) {
#pragma unroll
    for (int r = 0; r < 16; ++r) {
      Opart[w - 1][0][r][l] = make_float2(oA0[r], oA1[r]);
      Opart[w - 1][1][r][l] = make_float2(oB0[r], oB1[r]);
    }
    if (l < 32) { Lpart[w - 1][0][l] = ls0; Lpart[w - 1][1][l] = ls1; }
  }
  __syncthreads();
  if (w == 0) {
    float lt0 = ls0 + Lpart[0][0][ql] + Lpart[1][0][ql] + Lpart[2][0][ql];
    float lt1 = ls1 + Lpart[0][1][ql] + Lpart[1][1][ql] + Lpart[2][1][ql];
    if (l < 32) { Linv[0][l] = 1.0f / lt0; Linv[1][l] = 1.0f / lt1; }
#pragma unroll
    for (int r = 0; r < 16; ++r) {
      float2 t0 = Opart[0][0][r][l], t1 = Opart[1][0][r][l], t2 = Opart[2][0][r][l];
      oA0[r] += t0.x + t1.x + t2.x;
      oA1[r] += t0.y + t1.y + t2.y;
      float2 u0 = Opart[0][1][r][l], u1 = Opart[1][1][r][l], u2 = Opart[2][1][r][l];
      oB0[r] += u0.x + u1.x + u2.x;
      oB1[r] += u0.y + u1.y + u2.y;
    }
#pragma unroll
    for (int r = 0; r < 16; ++r) {
      int qr = (r & 3) + 8 * (r >> 2) + 4 * hi;
      float li0 = Linv[0][qr];
      float li1 = Linv[1][qr];
      unsigned short* zp0 = Z + ((long)(b * 2048 + c0 * 32 + qr) * 768 + hd * 64 + ql);
      unsigned short* zp1 = Z + ((long)(b * 2048 + c1 * 32 + qr) * 768 + hd * 64 + ql);
      zp0[0]  = f2bf(oA0[r] * li0);
      zp0[32] = f2bf(oA1[r] * li0);
      zp1[0]  = f2bf(oB0[r] * li1);
      zp1[32] = f2bf(oB1[r] * li1);
    }
  }
}

extern "C" void kernel_launch(void* const* d_in, const int* in_sizes, int n_in,
                              void* d_out, int out_size, void* d_ws, size_t ws_size,
                              hipStream_t stream) {
  const float* x  = (const float*)d_in[0];
  const float* wk = (const float*)d_in[1];
  const float* wq = (const float*)d_in[2];
  const float* wv = (const float*)d_in[3];
  const float* wo = (const float*)d_in[4];

  unsigned short* ws = (unsigned short*)d_ws;
  unsigned short* x_bf  = ws;                    // 3145728 (row-major bf16)
  unsigned short* wkqv4 = x_bf + 3145728;        // 1769472 (B4 tiled)
  unsigned short* wo4   = wkqv4 + 1769472;       // 589824  (B4 tiled)
  unsigned short* qb    = wo4 + 589824;          // 3145728 each
  unsigned short* k4b   = qb + 3145728;
  unsigned short* v4b   = k4b + 3145728;
  unsigned short* zb    = v4b + 3145728;

  cvt_all<<<5376, 256, 0, stream>>>(x, wk, wq, wv, wo, x_bf, wkqv4, wo4);
  gemm_qkv<<<768, 256, 0, stream>>>(x_bf, wkqv4, k4b, qb, v4b);
  attn<<<768, 256, 0, stream>>>(qb, k4b, v4b, zb);
  gemm_out<<<256, 256, 0, stream>>>(zb, wo4, (float*)d_out);
}

// Round 19
// 73.684 us; speedup vs baseline: 1.0831x; 1.0831x over previous
//
#include <hip/hip_runtime.h>
#include <hip/hip_bf16.h>

typedef __attribute__((ext_vector_type(8))) short bf16x8;
typedef __attribute__((ext_vector_type(4))) float f32x4;
typedef __attribute__((ext_vector_type(16))) float f32x16;

static __device__ __forceinline__ unsigned short f2bf(float f) {
  union { float f; unsigned int u; } v; v.f = f;
  unsigned int u = v.u;
  return (unsigned short)((u + 0x7FFFu + ((u >> 16) & 1u)) >> 16);
}

__device__ __forceinline__ void async_ld16(const void* g, void* l) {
  __builtin_amdgcn_global_load_lds(
      (const __attribute__((address_space(1))) unsigned int*)g,
      (__attribute__((address_space(3))) unsigned int*)l, 16, 0, 0);
}

// fp32 -> bf16. x -> linear x_bf; Wk/Wq/Wv -> B4-tiled wkqv4 (rows 0..2303,
// Wq scaled by 0.125*log2e); Wo -> B4-tiled wo4. B4: [m/16][k/32][16][32].
__global__ __launch_bounds__(256) void cvt_all(
    const float* __restrict__ x, const float* __restrict__ wk,
    const float* __restrict__ wq, const float* __restrict__ wv,
    const float* __restrict__ wo,
    unsigned short* __restrict__ x_bf, unsigned short* __restrict__ wkqv4,
    unsigned short* __restrict__ wo4) {
  int i = blockIdx.x * 256 + threadIdx.x;
  int e0 = i * 4;
  if (e0 < 3145728) {
    float4 v = *(const float4*)(x + e0);
    ushort4 r;
    r.x = f2bf(v.x); r.y = f2bf(v.y); r.z = f2bf(v.z); r.w = f2bf(v.w);
    *(ushort4*)(x_bf + e0) = r;
    return;
  }
  int j = e0 - 3145728;
  int a = j / 589824;
  int off = j - a * 589824;
  int nl = off / 768;
  int k = off - nl * 768;
  const float* src;
  unsigned short* dst;
  int m;
  float scale = 1.0f;
  if (a == 0)      { src = wk; m = nl;        dst = wkqv4; }
  else if (a == 1) { src = wq; m = 768 + nl;  dst = wkqv4; scale = 0.18033688011112042f; }
  else if (a == 2) { src = wv; m = 1536 + nl; dst = wkqv4; }
  else             { src = wo; m = nl;        dst = wo4; }
  float4 v = *(const float4*)(src + off);
  long idx = ((long)(m >> 4) * 24 + (k >> 5)) * 512 + (m & 15) * 32 + (k & 31);
  ushort4 r;
  r.x = f2bf(v.x * scale); r.y = f2bf(v.y * scale);
  r.z = f2bf(v.z * scale); r.w = f2bf(v.w * scale);
  *(ushort4*)(dst + idx) = r;
}

// 128x96 tile GEMM, BK=64. A: row-major, dbuf LDS (2x16KB), counted vmcnt.
// B: B4 fragment-tiled, register-direct with 1-deep prefetch (named sets).
// ONE barrier per K-step (WAR on As[cur^1] ordered by the next step's barrier).
// vmcnt(6) at step k retires {B_k(6), stage_k(4)} leaving B_{k+1}(6) in flight.
// MODE 0: fused QKV epilogue; MODE 1: fp32 linear out.
template <int MODE>
__device__ __forceinline__ void gemm_body(
    const unsigned short* __restrict__ A,
    const unsigned short* __restrict__ B4,
    void* __restrict__ outK, void* __restrict__ outQ, void* __restrict__ outV,
    int m0, int n0,
    unsigned short (*As)[8192]) {
  const int tid = threadIdx.x;
  const int w = tid >> 6;
  const int l = tid & 63;
  const int g = l >> 4;
  const int c = l & 15;
  const int wr = w >> 1, wc = w & 1;

  f32x4 acc[4][3];
#pragma unroll
  for (int i = 0; i < 4; i++)
#pragma unroll
    for (int j = 0; j < 3; j++) acc[i][j] = (f32x4){0.f, 0.f, 0.f, 0.f};

  const int lrow = l >> 3;
  const int lcolx = ((l & 7) ^ lrow) * 8;
  const unsigned short* pB = B4 + (long)((n0 >> 4) + wc * 3) * 12288 + c * 32 + g * 8;

  auto stageA = [&](int buf, int kt) {
    const int k0 = kt * 64;
#pragma unroll
    for (int cc = 0; cc < 4; ++cc) {
      int chunk = cc * 4 + w;                 // 16 chunks of 8 rows x 64 cols
      int row = chunk * 8 + lrow;
      async_ld16(A + (long)(m0 + row) * 768 + k0 + lcolx, &As[buf][chunk * 512]);
    }
  };
  auto loadB = [&](bf16x8 (*b)[3], int kt) {
#pragma unroll
    for (int ks = 0; ks < 2; ++ks)
#pragma unroll
      for (int ni = 0; ni < 3; ++ni)
        b[ks][ni] = *(const bf16x8*)(pB + (long)ni * 12288 + (kt * 2 + ks) * 512);
  };

  bf16x8 b0[2][3], b1[2][3];
  stageA(0, 0);
  loadB(b0, 0);

#pragma unroll
  for (int kt = 0; kt < 12; kt += 2) {
    // ---- even step kt (buf 0, uses b0) ----
    if (kt + 1 < 12) loadB(b1, kt + 1);
    __builtin_amdgcn_sched_barrier(0);
    asm volatile("s_waitcnt vmcnt(6)" ::: "memory");
    __builtin_amdgcn_sched_barrier(0);
    __builtin_amdgcn_s_barrier();
    __builtin_amdgcn_sched_barrier(0);
    if (kt + 1 < 12) stageA(1, kt + 1);
#pragma unroll
    for (int ks = 0; ks < 2; ++ks) {
      bf16x8 a[4];
#pragma unroll
      for (int mi = 0; mi < 4; ++mi) {
        int row = wr * 64 + mi * 16 + c;
        int col = (ks * 32 + g * 8) ^ ((row & 7) * 8);
        a[mi] = *(const bf16x8*)&As[0][row * 64 + col];
      }
#pragma unroll
      for (int mi = 0; mi < 4; ++mi)
#pragma unroll
        for (int ni = 0; ni < 3; ++ni)
          acc[mi][ni] = __builtin_amdgcn_mfma_f32_16x16x32_bf16(a[mi], b0[ks][ni], acc[mi][ni], 0, 0, 0);
    }
    // ---- odd step kt+1 (buf 1, uses b1) ----
    if (kt + 2 < 12) loadB(b0, kt + 2);
    __builtin_amdgcn_sched_barrier(0);
    if (kt + 2 < 12) {
      asm volatile("s_waitcnt vmcnt(6)" ::: "memory");
    } else {
      asm volatile("s_waitcnt vmcnt(0)" ::: "memory");
    }
    __builtin_amdgcn_sched_barrier(0);
    __builtin_amdgcn_s_barrier();
    __builtin_amdgcn_sched_barrier(0);
    if (kt + 2 < 12) stageA(0, kt + 2);
#pragma unroll
    for (int ks = 0; ks < 2; ++ks) {
      bf16x8 a[4];
#pragma unroll
      for (int mi = 0; mi < 4; ++mi) {
        int row = wr * 64 + mi * 16 + c;
        int col = (ks * 32 + g * 8) ^ ((row & 7) * 8);
        a[mi] = *(const bf16x8*)&As[1][row * 64 + col];
      }
#pragma unroll
      for (int mi = 0; mi < 4; ++mi)
#pragma unroll
        for (int ni = 0; ni < 3; ++ni)
          acc[mi][ni] = __builtin_amdgcn_mfma_f32_16x16x32_bf16(a[mi], b1[ks][ni], acc[mi][ni], 0, 0, 0);
    }
  }

  if (MODE == 1) {
    float* O = (float*)outK;
#pragma unroll
    for (int mi = 0; mi < 4; ++mi)
#pragma unroll
      for (int ni = 0; ni < 3; ++ni)
#pragma unroll
        for (int r = 0; r < 4; ++r) {
          int m = m0 + wr * 64 + mi * 16 + g * 4 + r;
          int n = n0 + wc * 48 + ni * 16 + c;
          O[(long)m * 768 + n] = acc[mi][ni][r];
        }
  } else {
    const int which = (n0 >= 1536) ? 2 : (n0 >= 768 ? 1 : 0);
    const int nb = n0 - which * 768;
    const int b = m0 >> 11;                    // block-uniform
    if (which == 2) {
      // V4 tiled [bh][p/16][e][p&15]: r=0..3 contiguous in p&15 -> ushort4
#pragma unroll
      for (int mi = 0; mi < 4; ++mi)
#pragma unroll
        for (int ni = 0; ni < 3; ++ni) {
          int e = nb + wc * 48 + ni * 16 + c;
          int h = e >> 6, el = e & 63;
          long bh = b * 12 + h;
          int p0 = (m0 & 2047) + wr * 64 + mi * 16 + g * 4;
          long idx = bh * 131072 + (p0 >> 4) * 1024 + el * 16 + (p0 & 15);
          ushort4 pk;
          pk.x = f2bf(acc[mi][ni][0]); pk.y = f2bf(acc[mi][ni][1]);
          pk.z = f2bf(acc[mi][ni][2]); pk.w = f2bf(acc[mi][ni][3]);
          *(ushort4*)&((unsigned short*)outV)[idx] = pk;
        }
    } else {
#pragma unroll
      for (int mi = 0; mi < 4; ++mi)
#pragma unroll
        for (int ni = 0; ni < 3; ++ni)
#pragma unroll
          for (int r = 0; r < 4; ++r) {
            int m = m0 + wr * 64 + mi * 16 + g * 4 + r;
            int nn = nb + wc * 48 + ni * 16 + c;
            int p = m & 2047;
            int h = nn >> 6, e = nn & 63;
            unsigned short val = f2bf(acc[mi][ni][r]);
            long bh = b * 12 + h;
            if (which == 0) {
              // K4 tiled: [bh][p/32][d/16][p&31][d&15]
              long idx = bh * 131072 + (p >> 5) * 2048 + (e >> 4) * 512 + (p & 31) * 16 + (e & 15);
              ((unsigned short*)outK)[idx] = val;
            } else {
              ((unsigned short*)outQ)[((bh * 2048 + p) << 6) + e] = val;
            }
          }
    }
  }
}

// grid 768 (1D) = 3 blocks/CU. XCD-chunked: xcd = bid&7 owns 8m x 12n panel.
__global__ __launch_bounds__(256) void gemm_qkv(
    const unsigned short* __restrict__ A,
    const unsigned short* __restrict__ Wkqv4,  // B4-tiled [Wk;Wq;Wv]
    unsigned short* __restrict__ k4b, unsigned short* __restrict__ qb,
    unsigned short* __restrict__ v4b) {
  __shared__ __align__(16) unsigned short As[2][8192];
  const int lb = blockIdx.x;
  const int xcd = lb & 7, idx = lb >> 3;       // idx 0..95
  const int mg = xcd >> 1, ng = xcd & 1;
  const int mi = idx / 12, ni = idx - 12 * mi; // ni fastest shares A-tile
  gemm_body<0>(A, Wkqv4, k4b, qb, v4b, (mg * 8 + mi) * 128, (ng * 12 + ni) * 96, As);
}

// grid 256 (1D) = 1 block/CU. xcd = bid&7 owns 4m x 8n panel.
__global__ __launch_bounds__(256) void gemm_out(
    const unsigned short* __restrict__ A,
    const unsigned short* __restrict__ Wo4,
    float* __restrict__ out) {
  __shared__ __align__(16) unsigned short As[2][8192];
  const int lb = blockIdx.x;
  const int xcd = lb & 7, idx = lb >> 3;       // idx 0..31
  const int mi = idx >> 3, ni = idx & 7;
  gemm_body<1>(A, Wo4, out, nullptr, nullptr, (xcd * 4 + mi) * 128, ni * 96, As);
}

// causal flash attention: swapped QK^T (32x32x16), in-register softmax,
// DUAL-CHUNK FUSED (round-17 loop: 2-deep K/V rotation, no setprio) +
// ALL-WAVE PARALLEL EPILOGUE: every wave writes partials; wave w combines
// and stores register-quarter r in [4w, 4w+4) for both chunks.
__global__ __launch_bounds__(256, 2) void attn(
    const unsigned short* __restrict__ Q,
    const unsigned short* __restrict__ K4,
    const unsigned short* __restrict__ V4,
    unsigned short* __restrict__ Z) {
  __shared__ float2 Opart[4][2][16][64];   // 64 KB
  __shared__ float Lpart[4][2][32];
  const int bx = blockIdx.x;                   // 0..767
  const int cidx = bx / 24;                    // 0..31 (pair index)
  const int bh = bx - cidx * 24;               // bh fastest (round-13 proven)
  const int pp = 31 - cidx;                    // LPT: big pairs first
  const int c0 = 2 * pp, c1 = 2 * pp + 1;
  const int tid = threadIdx.x;
  const int w = tid >> 6;                      // k-parity 0..3
  const int l = tid & 63;
  const int ql = l & 31;
  const int hi = l >> 5;
  const int b = bh / 12, hd = bh - b * 12;
  const long base = (long)bh * 2048 * 64;

  // Q B-fragments for both chunks
  bf16x8 qf0[4], qf1[4];
  {
    const unsigned short* qp0 = Q + base + (long)(c0 * 32 + ql) * 64 + hi * 8;
    const unsigned short* qp1 = Q + base + (long)(c1 * 32 + ql) * 64 + hi * 8;
#pragma unroll
    for (int d = 0; d < 4; ++d) {
      qf0[d] = *(const bf16x8*)(qp0 + d * 16);
      qf1[d] = *(const bf16x8*)(qp1 + d * 16);
    }
  }

  f32x16 oA0, oA1, oB0, oB1;
#pragma unroll
  for (int r = 0; r < 16; ++r) { oA0[r] = 0.f; oA1[r] = 0.f; oB0[r] = 0.f; oB1[r] = 0.f; }
  float ls0 = 0.f, ls1 = 0.f;

  const unsigned short* kp = K4 + (long)bh * 131072 + ql * 16 + hi * 8;
  const unsigned short* vp = V4 + (long)bh * 131072 + ql * 16 + hi * 8;

  auto loadsub = [&](bf16x8* kf, bf16x8* v0, bf16x8* v1, int s) {
    const unsigned short* kps = kp + (long)s * 2048;
#pragma unroll
    for (int d = 0; d < 4; ++d) kf[d] = *(const bf16x8*)(kps + d * 512);
    const unsigned short* vps = vp + (long)s * 2048;
    v0[0] = *(const bf16x8*)(vps);
    v0[1] = *(const bf16x8*)(vps + 1024);
    v1[0] = *(const bf16x8*)(vps + 512);
    v1[1] = *(const bf16x8*)(vps + 1536);
  };

  auto comp_pair = [&](const bf16x8* kf, const bf16x8* v0, const bf16x8* v1, int s) {
    const bool do0 = (s <= c0);
    // ---- QK for BOTH chunks first: two independent MFMA chains ----
    f32x16 s1_, s0_;
#pragma unroll
    for (int r = 0; r < 16; ++r) { s1_[r] = 0.f; s0_[r] = 0.f; }
#pragma unroll
    for (int d = 0; d < 4; ++d)
      s1_ = __builtin_amdgcn_mfma_f32_32x32x16_bf16(kf[d], qf1[d], s1_, 0, 0, 0);
    if (do0) {
#pragma unroll
      for (int d = 0; d < 4; ++d)
        s0_ = __builtin_amdgcn_mfma_f32_32x32x16_bf16(kf[d], qf0[d], s0_, 0, 0, 0);
    }
    // ---- chunk1: mask, softmax, PV ----
    if (s == c1) {
#pragma unroll
      for (int r = 0; r < 16; ++r) {
        int krow = (r & 3) + 8 * (r >> 2) + 4 * hi;
        s1_[r] = (krow <= ql) ? s1_[r] : -1e30f;
      }
    }
    {
      float p[16];
#pragma unroll
      for (int r = 0; r < 16; ++r) { p[r] = exp2f(s1_[r]); ls1 += p[r]; }
      unsigned int wpk[8];
#pragma unroll
      for (int i = 0; i < 8; ++i)
        asm("v_cvt_pk_bf16_f32 %0, %1, %2" : "=v"(wpk[i]) : "v"(p[2 * i]), "v"(p[2 * i + 1]));
      asm volatile("v_permlane32_swap_b32 %0, %1" : "+v"(wpk[0]), "+v"(wpk[2]));
      asm volatile("v_permlane32_swap_b32 %0, %1" : "+v"(wpk[1]), "+v"(wpk[3]));
      asm volatile("v_permlane32_swap_b32 %0, %1" : "+v"(wpk[4]), "+v"(wpk[6]));
      asm volatile("v_permlane32_swap_b32 %0, %1" : "+v"(wpk[5]), "+v"(wpk[7]));
      union { unsigned int u[4]; bf16x8 v; } f0, f1;
      f0.u[0] = wpk[0]; f0.u[1] = wpk[1]; f0.u[2] = wpk[2]; f0.u[3] = wpk[3];
      f1.u[0] = wpk[4]; f1.u[1] = wpk[5]; f1.u[2] = wpk[6]; f1.u[3] = wpk[7];
      oB0 = __builtin_amdgcn_mfma_f32_32x32x16_bf16(f0.v, v0[0], oB0, 0, 0, 0);
      oB1 = __builtin_amdgcn_mfma_f32_32x32x16_bf16(f0.v, v1[0], oB1, 0, 0, 0);
      oB0 = __builtin_amdgcn_mfma_f32_32x32x16_bf16(f1.v, v0[1], oB0, 0, 0, 0);
      oB1 = __builtin_amdgcn_mfma_f32_32x32x16_bf16(f1.v, v1[1], oB1, 0, 0, 0);
    }
    // ---- chunk0: mask, softmax, PV ----
    if (do0) {
      if (s == c0) {
#pragma unroll
        for (int r = 0; r < 16; ++r) {
          int krow = (r & 3) + 8 * (r >> 2) + 4 * hi;
          s0_[r] = (krow <= ql) ? s0_[r] : -1e30f;
        }
      }
      float p[16];
#pragma unroll
      for (int r = 0; r < 16; ++r) { p[r] = exp2f(s0_[r]); ls0 += p[r]; }
      unsigned int wpk[8];
#pragma unroll
      for (int i = 0; i < 8; ++i)
        asm("v_cvt_pk_bf16_f32 %0, %1, %2" : "=v"(wpk[i]) : "v"(p[2 * i]), "v"(p[2 * i + 1]));
      asm volatile("v_permlane32_swap_b32 %0, %1" : "+v"(wpk[0]), "+v"(wpk[2]));
      asm volatile("v_permlane32_swap_b32 %0, %1" : "+v"(wpk[1]), "+v"(wpk[3]));
      asm volatile("v_permlane32_swap_b32 %0, %1" : "+v"(wpk[4]), "+v"(wpk[6]));
      asm volatile("v_permlane32_swap_b32 %0, %1" : "+v"(wpk[5]), "+v"(wpk[7]));
      union { unsigned int u[4]; bf16x8 v; } f0, f1;
      f0.u[0] = wpk[0]; f0.u[1] = wpk[1]; f0.u[2] = wpk[2]; f0.u[3] = wpk[3];
      f1.u[0] = wpk[4]; f1.u[1] = wpk[5]; f1.u[2] = wpk[6]; f1.u[3] = wpk[7];
      oA0 = __builtin_amdgcn_mfma_f32_32x32x16_bf16(f0.v, v0[0], oA0, 0, 0, 0);
      oA1 = __builtin_amdgcn_mfma_f32_32x32x16_bf16(f0.v, v1[0], oA1, 0, 0, 0);
      oA0 = __builtin_amdgcn_mfma_f32_32x32x16_bf16(f1.v, v0[1], oA0, 0, 0, 0);
      oA1 = __builtin_amdgcn_mfma_f32_32x32x16_bf16(f1.v, v1[1], oA1, 0, 0, 0);
    }
  };

  int s = w;
  if (s <= c1) {
    bf16x8 kfA[4], vA0[2], vA1[2], kfB[4], vB0[2], vB1[2];
    loadsub(kfA, vA0, vA1, s);
    while (s + 8 <= c1) {
      loadsub(kfB, vB0, vB1, s + 4);
      comp_pair(kfA, vA0, vA1, s);
      loadsub(kfA, vA0, vA1, s + 8);
      comp_pair(kfB, vB0, vB1, s + 4);
      s += 8;
    }
    if (s + 4 <= c1) {
      loadsub(kfB, vB0, vB1, s + 4);
      comp_pair(kfA, vA0, vA1, s);
      comp_pair(kfB, vB0, vB1, s + 4);
    } else {
      comp_pair(kfA, vA0, vA1, s);
    }
  }

  ls0 += __shfl_xor(ls0, 32);
  ls1 += __shfl_xor(ls1, 32);

  // ---- all-wave parallel split-k combine ----
#pragma unroll
  for (int r = 0; r < 16; ++r) {
    Opart[w][0][r][l] = make_float2(oA0[r], oA1[r]);
    Opart[w][1][r][l] = make_float2(oB0[r], oB1[r]);
  }
  if (l < 32) { Lpart[w][0][l] = ls0; Lpart[w][1][l] = ls1; }
  __syncthreads();

  float lt0 = Lpart[0][0][ql] + Lpart[1][0][ql] + Lpart[2][0][ql] + Lpart[3][0][ql];
  float lt1 = Lpart[0][1][ql] + Lpart[1][1][ql] + Lpart[2][1][ql] + Lpart[3][1][ql];
  float li0me = 1.0f / lt0;
  float li1me = 1.0f / lt1;

#pragma unroll
  for (int rr = 0; rr < 4; ++rr) {
    int r = w * 4 + rr;
    float2 a0 = Opart[0][0][r][l], a1 = Opart[1][0][r][l];
    float2 a2 = Opart[2][0][r][l], a3 = Opart[3][0][r][l];
    float x0 = a0.x + a1.x + a2.x + a3.x;
    float x1 = a0.y + a1.y + a2.y + a3.y;
    float2 b0 = Opart[0][1][r][l], b1 = Opart[1][1][r][l];
    float2 b2 = Opart[2][1][r][l], b3 = Opart[3][1][r][l];
    float y0 = b0.x + b1.x + b2.x + b3.x;
    float y1 = b0.y + b1.y + b2.y + b3.y;
    int qr = (r & 3) + 8 * (r >> 2) + 4 * hi;
    float li0 = __shfl(li0me, qr);
    float li1 = __shfl(li1me, qr);
    unsigned short* zp0 = Z + ((long)(b * 2048 + c0 * 32 + qr) * 768 + hd * 64 + ql);
    unsigned short* zp1 = Z + ((long)(b * 2048 + c1 * 32 + qr) * 768 + hd * 64 + ql);
    zp0[0]  = f2bf(x0 * li0);
    zp0[32] = f2bf(x1 * li0);
    zp1[0]  = f2bf(y0 * li1);
    zp1[32] = f2bf(y1 * li1);
  }
}

extern "C" void kernel_launch(void* const* d_in, const int* in_sizes, int n_in,
                              void* d_out, int out_size, void* d_ws, size_t ws_size,
                              hipStream_t stream) {
  const float* x  = (const float*)d_in[0];
  const float* wk = (const float*)d_in[1];
  const float* wq = (const float*)d_in[2];
  const float* wv = (const float*)d_in[3];
  const float* wo = (const float*)d_in[4];

  unsigned short* ws = (unsigned short*)d_ws;
  unsigned short* x_bf  = ws;                    // 3145728 (row-major bf16)
  unsigned short* wkqv4 = x_bf + 3145728;        // 1769472 (B4 tiled)
  unsigned short* wo4   = wkqv4 + 1769472;       // 589824  (B4 tiled)
  unsigned short* qb    = wo4 + 589824;          // 3145728 each
  unsigned short* k4b   = qb + 3145728;
  unsigned short* v4b   = k4b + 3145728;
  unsigned short* zb    = v4b + 3145728;

  cvt_all<<<5376, 256, 0, stream>>>(x, wk, wq, wv, wo, x_bf, wkqv4, wo4);
  gemm_qkv<<<768, 256, 0, stream>>>(x_bf, wkqv4, k4b, qb, v4b);
  attn<<<768, 256, 0, stream>>>(qb, k4b, v4b, zb);
  gemm_out<<<256, 256, 0, stream>>>(zb, wo4, (float*)d_out);
}